// Round 5
// baseline (205.675 us; speedup 1.0000x reference)
//
#include <hip/hip_runtime.h>

#define DEV_INLINE __device__ __forceinline__

// Native 16B vector type — __builtin_nontemporal_store requires a native
// clang ext-vector (HIP's float4 is a class and is rejected).
typedef float f32x4 __attribute__((ext_vector_type(4)));

// Numerically stable softplus: max(v,0) + log1p(exp(-|v|)).
DEV_INLINE float softplus_f(float v) {
    return fmaxf(v, 0.0f) + __logf(1.0f + __expf(-fabsf(v)));
}

// One thread = one row (token). Two-phase, wave-private LDS staging:
// each wave transposes rows 0-31 then rows 32-63 through the SAME 4.5 KB
// slice (18 KB/block total vs 36 KB single-phase) -> LDS allows 8 blocks/CU
// instead of 4. No block barrier anywhere: the exchange is intra-wave, so
// s_waitcnt lgkmcnt(0) suffices (LDS ops of one wave complete in order
// behind it). launch_bounds(256,6) asks the allocator for >=6 waves/SIMD.
//
// Stores are non-temporal full-line 1 KiB-per-instruction bursts: the
// 144 MiB output is written once and never re-read.
__global__ __launch_bounds__(256, 6) void pb_kernel(
    const float* __restrict__ x,
    const float* __restrict__ W_in, const float* __restrict__ b_in,
    const float* __restrict__ W1,   const float* __restrict__ b1,
    const float* __restrict__ W2,   const float* __restrict__ b2,
    const float* __restrict__ W3,   const float* __restrict__ b3,
    const float* __restrict__ W4,   const float* __restrict__ b4,
    const float* __restrict__ W_out,const float* __restrict__ b_out,
    float* __restrict__ out, int n_rows)
{
    __shared__ f32x4 sbuf[4 * 288];   // 18 KB: 4 waves x (32 rows x 9 float4)

    const int tid  = threadIdx.x;
    const int lane = tid & 63;
    const int wv   = tid >> 6;

    const int row_raw = blockIdx.x * 256 + tid;
    const int row = row_raw < n_rows ? row_raw : n_rows - 1;  // clamp (grid exact anyway)

    // ---- load one row of x (6 floats, 24B stride -> three float2 loads) ----
    const float2* xv = (const float2*)(x + (size_t)row * 6);
    const float2 p0 = xv[0], p1 = xv[1], p2 = xv[2];
    const float xin[6] = { p0.x, p0.y, p1.x, p1.y, p2.x, p2.y };

    // ---- input layer 6 -> 8 ----
    float y[8];
    #pragma unroll
    for (int o = 0; o < 8; ++o) {
        float acc = b_in[o];
        #pragma unroll
        for (int i = 0; i < 6; ++i)
            acc = fmaf(W_in[o * 6 + i], xin[i], acc);
        y[o] = softplus_f(acc);
    }

    // ---- 4 hidden layers 8 -> 8 ----
    const float* Ws[4] = { W1, W2, W3, W4 };
    const float* bs[4] = { b1, b2, b3, b4 };
    #pragma unroll
    for (int l = 0; l < 4; ++l) {
        const float* __restrict__ W = Ws[l];
        const float* __restrict__ b = bs[l];
        float t[8];
        #pragma unroll
        for (int o = 0; o < 8; ++o) {
            float acc = b[o];
            #pragma unroll
            for (int i = 0; i < 8; ++i)
                acc = fmaf(W[o * 8 + i], y[i], acc);
            t[o] = softplus_f(acc);
        }
        #pragma unroll
        for (int o = 0; o < 8; ++o) y[o] = t[o];
    }

    // ---- output layer 8 -> 15 ----
    float u[15];
    #pragma unroll
    for (int o = 0; o < 15; ++o) {
        float acc = b_out[o];
        #pragma unroll
        for (int i = 0; i < 8; ++i)
            acc = fmaf(W_out[o * 8 + i], y[i], acc);
        u[o] = acc;
    }

    // ---- the 9 float4 chunks of the antisymmetric 6x6, straight from u ----
    // L rows: {0,u0,u1,u2,u3,u4 | -u0,0,u5,u6,u7,u8 | -u1,-u5,0,u9,u10,u11 |
    //          -u2,-u6,-u9,0,u12,u13 | -u3,-u7,-u10,-u12,0,u14 |
    //          -u4,-u8,-u11,-u13,-u14,0}
    f32x4 c0 = {  0.0f,  u[0],   u[1],   u[2]  };
    f32x4 c1 = {  u[3],  u[4],  -u[0],   0.0f  };
    f32x4 c2 = {  u[5],  u[6],   u[7],   u[8]  };
    f32x4 c3 = { -u[1], -u[5],   0.0f,   u[9]  };
    f32x4 c4 = {  u[10], u[11], -u[2],  -u[6]  };
    f32x4 c5 = { -u[9],  0.0f,   u[12],  u[13] };
    f32x4 c6 = { -u[3], -u[7],  -u[10], -u[12] };
    f32x4 c7 = {  0.0f,  u[14], -u[4],  -u[8]  };
    f32x4 c8 = { -u[11],-u[13], -u[14],  0.0f  };

    f32x4* wbuf = sbuf + wv * 288;
    const long long wave_f4 = ((long long)blockIdx.x * 256 + (wv << 6)) * 9;
    f32x4* __restrict__ dst = (f32x4*)out + wave_f4;
    const long long total_f4 = (long long)n_rows * 9;
    const bool full = (wave_f4 + 576 <= total_f4);   // always true (grid exact)

    #pragma unroll
    for (int h = 0; h < 2; ++h) {
        // ---- write phase: lanes [32h, 32h+32) stage their 9 chunks ----
        if ((lane >> 5) == h) {
            f32x4* rb = wbuf + (lane & 31) * 9;
            rb[0] = c0; rb[1] = c1; rb[2] = c2;
            rb[3] = c3; rb[4] = c4; rb[5] = c5;
            rb[6] = c6; rb[7] = c7; rb[8] = c8;
        }
        // Drain this wave's LDS ops (writes now; and on h=1, the h=0 reads
        // that used these slots). Intra-wave only — no barrier.
        asm volatile("s_waitcnt lgkmcnt(0)" ::: "memory");

        // ---- read + wave-coalesced nt stores: 4.5 KB contiguous ----
        f32x4* __restrict__ dsth = dst + h * 288;
        if (full) {
            #pragma unroll
            for (int q = 0; q < 4; ++q) {
                const int idx = q * 64 + lane;
                __builtin_nontemporal_store(wbuf[idx], dsth + idx);
            }
            if (lane < 32) {
                const int idx = 256 + lane;
                __builtin_nontemporal_store(wbuf[idx], dsth + idx);
            }
        } else {                                  // tail safety (dead in practice)
            #pragma unroll
            for (int q = 0; q < 5; ++q) {
                const int idx = q * 64 + lane;
                if (idx < 288 && wave_f4 + h * 288 + idx < total_f4)
                    __builtin_nontemporal_store(wbuf[idx], dsth + idx);
            }
        }
        // End-of-half drain so h=1's ds_writes can't overtake h=0's ds_reads.
        asm volatile("s_waitcnt lgkmcnt(0)" ::: "memory");
    }
}

extern "C" void kernel_launch(void* const* d_in, const int* in_sizes, int n_in,
                              void* d_out, int out_size, void* d_ws, size_t ws_size,
                              hipStream_t stream) {
    const float* x     = (const float*)d_in[0];
    const float* W_in  = (const float*)d_in[1];
    const float* b_in  = (const float*)d_in[2];
    const float* W1    = (const float*)d_in[3];
    const float* b1    = (const float*)d_in[4];
    const float* W2    = (const float*)d_in[5];
    const float* b2    = (const float*)d_in[6];
    const float* W3    = (const float*)d_in[7];
    const float* b3    = (const float*)d_in[8];
    const float* W4    = (const float*)d_in[9];
    const float* b4    = (const float*)d_in[10];
    const float* W_out = (const float*)d_in[11];
    const float* b_out = (const float*)d_in[12];
    float* out = (float*)d_out;

    const int n_rows = in_sizes[0] / 6;           // B*T = 1,048,576
    const int block = 256;
    const int grid = (n_rows + block - 1) / block;

    hipLaunchKernelGGL(pb_kernel, dim3(grid), dim3(block), 0, stream,
                       x, W_in, b_in, W1, b1, W2, b2, W3, b3, W4, b4,
                       W_out, b_out, out, n_rows);
}